// Round 1
// 145.999 us; speedup vs baseline: 1.0232x; 1.0232x over previous
//
#include <hip/hip_runtime.h>
#include <hip/hip_bf16.h>

// CARAFE R7:
//  - k_prep: merged k_halo + k_repack + k_repack_woz into one dispatch
//    (block-aligned thread ranges: [0,64512) enc repack, [64512,146432)
//    wd/wo repack, [146432,188544) zT/downT halo clear).
//  - k_dzmfma: fused down+z GEMM (unchanged, verified).
//  - k_encmfma: enc conv MFMA GEMM (unchanged, verified). Writes RAW enc.
//  - k_fused_out v4: softmax over the 25 taps folded into phase 1 (in-LDS,
//    3-pass, 64 worker threads) -- k_softmax dispatch deleted. Rest unchanged.
// Pipeline: 4 dispatches (was 7). N=4, H=W=64, INC=256, CM=64, KUP=5,
// DELTA=2, enc_out=100, OUTC=256.

namespace {
constexpr int kN = 4, kH = 64, kW = 64, kINC = 256, kCM = 64;
constexpr int kENC = 100, kH2 = 128, kW2 = 128, kOUTC = 256;
constexpr int kHW = kH * kW;       // 4096
constexpr int kHW2 = kH2 * kW2;    // 16384
constexpr int kPadW = 66;          // 64 + 1 halo (enc 3x3)
constexpr int kTImg = kPadW * kPadW * kCM;    // 278784 (downT per image)
constexpr int kZPad = 68;          // 64 + 2 halo (reassembly 5x5)
constexpr int kZImg = kZPad * kZPad * kOUTC;  // 1183744 (zT per image)
// k_prep thread-range boundaries (all block-aligned except final tail):
constexpr int kPrepRepackEnc = 9 * 7 * 2 * 512;          // 64512  (252 blocks)
constexpr int kPrepRepackWoz = 8 * 20 * 512;             // 81920  (320 blocks)
constexpr int kPrepHaloZ = 4 * 528 * 16;                 // 33792
constexpr int kPrepHaloD = 4 * 260 * 8;                  // 8320
constexpr int kPrepTotal = kPrepRepackEnc + kPrepRepackWoz + kPrepHaloZ + kPrepHaloD; // 188544
}

typedef __attribute__((ext_vector_type(8))) short short8;   // 8 bf16
typedef __attribute__((ext_vector_type(4))) float floatx4;  // MFMA acc

static __device__ __forceinline__ unsigned short bf16bits(float f) {
  __hip_bfloat16 h = __float2bfloat16(f);
  return *(unsigned short*)&h;
}

// ---------- merged prep: weight repacks + halo clears (one dispatch) ----------
// Range 1 [0, 64512): repack enc weights into A-fragment order (R4, verified).
// Range 2 [64512, 146432): repack stacked [wd;wo] into A-frag order (R5, verified).
// Range 3 [146432, 188544): zT halo (528 px * 16 f4-chunks) + downT halo
//   (260 px * 8 f4-chunks) per image (R6, verified).
__global__ __launch_bounds__(256) void k_prep(
    const float* __restrict__ we, unsigned short* __restrict__ Aswz,
    const float* __restrict__ wd, const float* __restrict__ wo,
    unsigned short* __restrict__ Awoz,
    float* __restrict__ zT, __hip_bfloat16* __restrict__ downT) {
  const int t = blockIdx.x * 256 + threadIdx.x;
  if (t < kPrepRepackEnc) {
    const int e = t;
    const int j = e & 7, lane = (e >> 3) & 63, kh = (e >> 9) & 1, tm = e >> 10;
    const int mt = tm % 7, tap = tm / 7;
    const int o = mt * 16 + (lane & 15);
    const int ci = kh * 32 + ((lane >> 4) & 3) * 8 + j;
    const float v = (o < kENC) ? we[(size_t)o * 576 + ci * 9 + tap] : 0.f;
    Aswz[e] = bf16bits(v);
  } else if (t < kPrepRepackEnc + kPrepRepackWoz) {
    const int e = t - kPrepRepackEnc;
    const int j = e & 7, lane = (e >> 3) & 63;
    const int rest = e >> 9;
    const int mt = rest % 20, ks = rest / 20;
    const int r = mt * 16 + (lane & 15);
    const int k = ks * 32 + (lane >> 4) * 8 + j;
    const float v = (r < kCM) ? wd[(size_t)r * kINC + k]
                              : wo[(size_t)(r - kCM) * kINC + k];
    Awoz[e] = bf16bits(v);
  } else if (t < kPrepTotal) {
    const int u0 = t - (kPrepRepackEnc + kPrepRepackWoz);
    if (u0 < kPrepHaloZ) {
      const int chunk = u0 & 15, rest = u0 >> 4;
      const int i = rest % 528, n = rest / 528;
      int r, c;
      if (i < 272) { r = i / 68; if (r >= 2) r += 64; c = i % 68; }
      else { const int j = i - 272; r = 2 + (j >> 2); const int cc = j & 3; c = (cc < 2) ? cc : cc + 64; }
      float4* p = (float4*)(zT + (size_t)n * kZImg + ((size_t)r * kZPad + c) * kOUTC) + chunk;
      *p = make_float4(0.f, 0.f, 0.f, 0.f);
    } else {
      const int u = u0 - kPrepHaloZ;
      const int chunk = u & 7, rest = u >> 3;
      const int i = rest % 260, n = rest / 260;
      int r, c;
      if (i < 132) { r = (i / 66) ? 65 : 0; c = i % 66; }
      else { const int j = i - 132; r = 1 + (j >> 1); c = (j & 1) ? 65 : 0; }
      float4* p = (float4*)((char*)downT
                  + ((size_t)n * kTImg + ((size_t)r * kPadW + c) * kCM) * 2) + chunk;
      *p = make_float4(0.f, 0.f, 0.f, 0.f);
    }
  }
}

// ---------- fused down + z GEMM: M=320, K=256, N=16384 (R5, verified) ----------
__global__ __launch_bounds__(256) void k_dzmfma(
    const float* __restrict__ x, const unsigned short* __restrict__ Awoz,
    const float* __restrict__ bd, __hip_bfloat16* __restrict__ downT,
    float* __restrict__ zT) {
  const int b = blockIdx.x;
  const int pt = b & 255, n = b >> 8;
  const int wave = threadIdx.x >> 6, lane = threadIdx.x & 63;
  const int col = lane & 15, quad = lane >> 4;
  const int px = pt * 16 + col;
  const int h = px >> 6, w = px & 63;
  const float* xb = x + (size_t)n * kINC * kHW + px;

  floatx4 acc[5];
#pragma unroll
  for (int m = 0; m < 5; ++m) acc[m] = (floatx4){0.f, 0.f, 0.f, 0.f};

#pragma unroll
  for (int ks = 0; ks < 8; ++ks) {
    float xv[8];
#pragma unroll
    for (int j = 0; j < 8; ++j)
      xv[j] = xb[(size_t)(ks * 32 + quad * 8 + j) * kHW];
    short8 bf;
#pragma unroll
    for (int j = 0; j < 8; ++j) bf[j] = (short)bf16bits(xv[j]);
#pragma unroll
    for (int m = 0; m < 5; ++m) {
      const int wtile = wave * 5 + m;
      const short8 af = *(const short8*)(
          Awoz + ((size_t)(ks * 20 + wtile) * 64 + lane) * 8);
      acc[m] = __builtin_amdgcn_mfma_f32_16x16x32_bf16(af, bf, acc[m], 0, 0, 0);
    }
  }

#pragma unroll
  for (int m = 0; m < 5; ++m) {
    const int wtile = wave * 5 + m;
    const int r0 = wtile * 16 + quad * 4;
    if (wtile < 4) {
      union { unsigned short u[4]; uint2 v; } pk;
#pragma unroll
      for (int rr = 0; rr < 4; ++rr)
        pk.u[rr] = bf16bits(acc[m][rr] + bd[r0 + rr]);
      __hip_bfloat16* dst = downT + (size_t)n * kTImg
                            + ((h + 1) * kPadW + (w + 1)) * kCM + r0;
      *(uint2*)dst = pk.v;
    } else {
      const int o = r0 - kCM;
      float* dst = zT + (size_t)n * kZImg
                   + ((h + 2) * kZPad + (w + 2)) * kOUTC + o;
      *(float4*)dst = make_float4(acc[m][0], acc[m][1], acc[m][2], acc[m][3]);
    }
  }
}

// ---------- enc conv as MFMA GEMM -> enc fp32 (N,100,64,64) (R4, verified) ----------
// Writes RAW (pre-softmax) enc; softmax now happens inside k_fused_out.
__global__ __launch_bounds__(256) void k_encmfma(
    const __hip_bfloat16* __restrict__ downT,
    const unsigned short* __restrict__ Aswz,
    const float* __restrict__ be, float* __restrict__ enc) {
  const int b = blockIdx.x;                 // 1024: h(64) x mtp(4) x n(4)
  const int h = b & 63, mtp = (b >> 6) & 3, n = b >> 8;
  const int wave = threadIdx.x >> 6, lane = threadIdx.x & 63;
  const int w0 = wave << 4;
  const int col = lane & 15, quad = lane >> 4;
  const int mt0 = mtp * 2;
  const bool has2 = (mt0 + 1) < 7;
  const short* dT = (const short*)downT + (size_t)n * kTImg;
  floatx4 acc0 = {0.f, 0.f, 0.f, 0.f}, acc1 = {0.f, 0.f, 0.f, 0.f};
#pragma unroll
  for (int tap = 0; tap < 9; ++tap) {
    const int dh = tap / 3 - 1, dw = tap % 3 - 1;
    const int rowbase = ((h + 1 + dh) * kPadW + (w0 + col + 1 + dw)) * kCM
                        + quad * 8;
#pragma unroll
    for (int kh = 0; kh < 2; ++kh) {
      const short8 bf = *(const short8*)(dT + rowbase + kh * 32);
      const short8 a0 = *(const short8*)(
          Aswz + (((size_t)(tap * 7 + mt0) * 2 + kh) * 64 + lane) * 8);
      acc0 = __builtin_amdgcn_mfma_f32_16x16x32_bf16(a0, bf, acc0, 0, 0, 0);
      if (has2) {
        const short8 a1 = *(const short8*)(
            Aswz + (((size_t)(tap * 7 + mt0 + 1) * 2 + kh) * 64 + lane) * 8);
        acc1 = __builtin_amdgcn_mfma_f32_16x16x32_bf16(a1, bf, acc1, 0, 0, 0);
      }
    }
  }
  const int p = h * kW + w0 + col;
#pragma unroll
  for (int r = 0; r < 4; ++r) {
    const int o = mt0 * 16 + quad * 4 + r;
    if (o < kENC) enc[(size_t)(n * kENC + o) * kHW + p] = acc0[r] + be[o];
  }
  if (has2) {
#pragma unroll
    for (int r = 0; r < 4; ++r) {
      const int o = (mt0 + 1) * 16 + quad * 4 + r;
      if (o < kENC) enc[(size_t)(n * kENC + o) * kHW + p] = acc1[r] + be[o];
    }
  }
}

// ---------- fused softmax + reassembly + pixel shuffle + bias -> out (v4) ----------
// 4096 blocks: pt(256) x og(4) x n(4); 256 thr = 4 waves.
// Block tile: 16 px (one h row segment) x 64 o x 4 d.
// Phase 1: stage RAW kern[16 px][100 ch] in LDS from enc, then in-LDS softmax
//   over the 25 taps (64 worker threads, one per (px,d); 3 LDS passes, no
//   per-thread array -> no VGPR spike). Recomputed per og block (4x, trivial).
// Phase 2: taps: z float4 (lane-contiguous o) + kern ds_read_b128 -> 16 FMA.
// Phase 3: acc -> LDS (stride-65 pad, conflict-free) -> coalesced float4 out.
__global__ __launch_bounds__(256) void k_fused_out(
    const float* __restrict__ zT, const float* __restrict__ enc,
    const float* __restrict__ bo, float* __restrict__ out) {
  const int b = blockIdx.x;
  const int pt = b & 255, og = (b >> 8) & 3, n = b >> 10;
  const int tid = threadIdx.x;
  const int wave = tid >> 6, lane = tid & 63;
  const int h = pt >> 2, w0 = (pt & 3) << 4;   // 16-px segment [w0, w0+16)
  const int px0 = pt * 16;                     // linear px base

  __shared__ float lds[64 * 65];               // 16.6 KB; kern tile then acc^T
  float* kernLDS = lds;                        // [16 px][104] (pad 100->104)

  // --- phase 1a: stage raw kern tile ---
  {
    const int p = tid & 15, chb = tid >> 4;
#pragma unroll
    for (int r = 0; r < 7; ++r) {
      const int ch = r * 16 + chb;
      if (ch < kENC)
        kernLDS[p * 104 + ch] = enc[((size_t)n * kENC + ch) * kHW + px0 + p];
    }
  }
  __syncthreads();

  // --- phase 1b: in-LDS softmax over 25 taps, worker = (px, d) ---
  if (tid < 64) {
    const int p = tid >> 2, d = tid & 3;
    float* kb = kernLDS + p * 104 + d;         // taps at stride 4 floats
    float m = -1e30f;
#pragma unroll
    for (int k = 0; k < 25; ++k) m = fmaxf(m, kb[k * 4]);
    float s = 0.f;
#pragma unroll
    for (int k = 0; k < 25; ++k) {
      const float e = __expf(kb[k * 4] - m);
      kb[k * 4] = e;
      s += e;
    }
    const float inv = 1.f / s;
#pragma unroll
    for (int k = 0; k < 25; ++k) kb[k * 4] *= inv;
  }
  __syncthreads();

  // --- phase 2: 25 taps ---
  const int oc = lane & 15, pxi = lane >> 4;
  const int px_l = wave * 4 + pxi;             // [0,16)
  const int w = w0 + px_l;
  const int o_l = oc * 4;                      // [0,64) step 4
  const float* zb = zT + (size_t)n * kZImg + og * 64 + o_l;
  const float* kp = kernLDS + px_l * 104;
  float acc[4][4] = {};                        // [oi][d]
#pragma unroll
  for (int tap = 0; tap < 25; ++tap) {
    const int kh = tap / 5, kw = tap % 5;      // z idx: (h+2 + kh-2) = h+kh
    const float4 zf = *(const float4*)(
        zb + ((size_t)(h + kh) * kZPad + (w + kw)) * kOUTC);
    const float4 kf = *(const float4*)(kp + tap * 4);
    acc[0][0] += zf.x * kf.x; acc[0][1] += zf.x * kf.y; acc[0][2] += zf.x * kf.z; acc[0][3] += zf.x * kf.w;
    acc[1][0] += zf.y * kf.x; acc[1][1] += zf.y * kf.y; acc[1][2] += zf.y * kf.z; acc[1][3] += zf.y * kf.w;
    acc[2][0] += zf.z * kf.x; acc[2][1] += zf.z * kf.y; acc[2][2] += zf.z * kf.z; acc[2][3] += zf.z * kf.w;
    acc[3][0] += zf.w * kf.x; acc[3][1] += zf.w * kf.y; acc[3][2] += zf.w * kf.z; acc[3][3] += zf.w * kf.w;
  }

  // --- phase 3: transpose via LDS, coalesced stores ---
  __syncthreads();                             // kern tile fully consumed
#pragma unroll
  for (int oi = 0; oi < 4; ++oi)
#pragma unroll
    for (int d = 0; d < 4; ++d)
      lds[(o_l + oi) * 65 + px_l * 4 + d] = acc[oi][d];
  __syncthreads();

  const int ol2 = tid >> 2, q = tid & 3;       // thread: one o row, quarter
  const int o = og * 64 + ol2;
  const float bias = bo[o];
  const float* Trow = lds + ol2 * 65;
#pragma unroll
  for (int i = 0; i < 2; ++i) {
    float* row = out + ((size_t)(n * kOUTC + o) * kH2 + (2 * h + i)) * kW2 + 2 * w0;
#pragma unroll
    for (int s = 0; s < 2; ++s) {
      const int xb_ = s * 16 + q * 4;          // x offset in [0,32)
      float4 v;
      v.x = Trow[((xb_ + 0) >> 1) * 4 + i * 2 + ((xb_ + 0) & 1)] + bias;
      v.y = Trow[((xb_ + 1) >> 1) * 4 + i * 2 + ((xb_ + 1) & 1)] + bias;
      v.z = Trow[((xb_ + 2) >> 1) * 4 + i * 2 + ((xb_ + 2) & 1)] + bias;
      v.w = Trow[((xb_ + 3) >> 1) * 4 + i * 2 + ((xb_ + 3) & 1)] + bias;
      *(float4*)(row + xb_) = v;
    }
  }
}

extern "C" void kernel_launch(void* const* d_in, const int* in_sizes, int n_in,
                              void* d_out, int out_size, void* d_ws, size_t ws_size,
                              hipStream_t stream) {
  const float* x  = (const float*)d_in[0];   // (4,256,64,64)
  const float* wd = (const float*)d_in[1];   // (64,256,1,1)
  const float* bd = (const float*)d_in[2];   // (64,)
  const float* we = (const float*)d_in[3];   // (100,64,3,3)
  const float* be = (const float*)d_in[4];   // (100,)
  const float* wo = (const float*)d_in[5];   // (256,256,1,1)
  const float* bo = (const float*)d_in[6];   // (256,)
  float* out = (float*)d_out;                // (4,256,128,128)

  // workspace (all 16B-aligned):
  float* enc = (float*)d_ws;                          // 1,638,400 f
  float* zT  = enc + 1638400;                         // 4,734,976 f (padded 68x68)
  __hip_bfloat16* downT = (__hip_bfloat16*)(zT + 4734976);      // 1,115,136 bf16
  unsigned short* Aswz  = (unsigned short*)(downT + (size_t)kN * kTImg); // 64,512
  unsigned short* Awoz  = Aswz + 64512;                          // 81,920

  // 4 dispatches (was 7): prep(repacks+halo) -> dz GEMM -> enc GEMM -> fused out
  k_prep<<<737, 256, 0, stream>>>(we, Aswz, wd, wo, Awoz, zT, downT);
  k_dzmfma<<<1024, 256, 0, stream>>>(x, Awoz, bd, downT, zT);
  k_encmfma<<<1024, 256, 0, stream>>>(downT, Aswz, be, enc);
  k_fused_out<<<4096, 256, 0, stream>>>(zT, enc, bo, out);
}